// Round 5
// baseline (210.387 us; speedup 1.0000x reference)
//
#include <hip/hip_runtime.h>

// YOLOv1 loss — pure float4 streaming (copy-kernel shape).
// pred, labels: [B=16384, C=30, G=7, G=7] fp32. Output: scalar fp32.
// Each wave streams 2 whole images (2940 floats = 735 float4, exactly aligned)
// of BOTH tensors as float4. Per component: cls channels (>=10) accumulate
// obj*(p-l)^2 inline (obj from small LDS table); box channels (<10) are
// stashed to LDS and consumed by a per-cell box-loss phase.

constexpr int BATCH   = 16384;
constexpr int G       = 7;
constexpr int GG      = 49;
constexpr int IMG_F   = 30 * GG;       // 1470 floats per image per tensor
constexpr int TPB     = 256;
constexpr int WAVES   = TPB / 64;      // 4
constexpr int IPW     = 2;             // images per wave
constexpr int IPB     = WAVES * IPW;   // 8 images per block
constexpr int NBLK    = BATCH / IPB;   // 2048
constexpr int SPAN_F  = IPW * IMG_F;   // 2940 (== 0 mod 4 -> float4 aligned)
constexpr int SPAN_V4 = SPAN_F / 4;    // 735
constexpr int NIT     = (SPAN_V4 + 63) / 64;  // 12 lane-iterations
constexpr int CHUNK   = 6;
constexpr int NCHUNK  = NIT / CHUNK;   // 2

__device__ __forceinline__ float sq(float x) { return x * x; }

__global__ __launch_bounds__(TPB) void yolo_loss_partial(
    const float* __restrict__ pred,
    const float* __restrict__ lab,
    float* __restrict__ ws)
{
    __shared__ float obj_s[IPB * GG];        // 392 f:  (labels ch4 == 1) ? 1 : 0
    __shared__ float box_p[IPB * 10 * GG];   // 3920 f: pred  ch 0..9
    __shared__ float box_l[IPB * 8  * GG];   // 3136 f: label ch 0..3,5..8
    __shared__ float wsum[WAVES];

    const int t    = threadIdx.x;
    const int lane = t & 63;
    const int wid  = t >> 6;
    const size_t blk_f = (size_t)blockIdx.x * IPB * IMG_F;

    // ---- obj table for the block's 8 images (coalesced, 2 rounds) ----
    for (int j = t; j < IPB * GG; j += TPB) {
        const int im   = j / GG;
        const int cell = j - im * GG;
        const float v  = lab[blk_f + (size_t)im * IMG_F + 4 * GG + cell];
        obj_s[j] = (v == 1.0f) ? 1.0f : 0.0f;
    }
    __syncthreads();

    const int wimg = wid * IPW;
    const float4* P4 = (const float4*)(pred + blk_f + wid * SPAN_F);
    const float4* L4 = (const float4*)(lab  + blk_f + wid * SPAN_F);

    float acc = 0.0f;

    // ---- float4 stream over the wave's whole 2-image span, both tensors ----
    for (int chk = 0; chk < NCHUNK; ++chk) {
        float4 pp[CHUNK], ll[CHUNK];
        int   id[CHUNK];
        bool  vd[CHUNK];
#pragma unroll
        for (int j = 0; j < CHUNK; ++j) {
            const int idx = lane + 64 * (chk * CHUNK + j);
            vd[j] = idx < SPAN_V4;
            id[j] = vd[j] ? idx : 0;
            pp[j] = P4[id[j]];
            ll[j] = L4[id[j]];
        }
#pragma unroll
        for (int j = 0; j < CHUNK; ++j) {
            const int e0 = id[j] * 4;
            const float pq[4] = {pp[j].x, pp[j].y, pp[j].z, pp[j].w};
            const float lq[4] = {ll[j].x, ll[j].y, ll[j].z, ll[j].w};
#pragma unroll
            for (int q = 0; q < 4; ++q) {
                const int e    = e0 + q;
                const int im   = (e >= IMG_F) ? 1 : 0;
                const int r    = e - im * IMG_F;          // 0..1469
                const int c    = r / GG;                  // channel 0..29
                const int cell = r - c * GG;              // 0..48
                const int I    = wimg + im;
                if (c >= 10) {                            // cls region
                    const float w = obj_s[I * GG + cell];
                    const float d = pq[q] - lq[q];
                    acc += w * d * d;
                } else if (vd[j]) {                       // box region: stash
                    box_p[I * (10 * GG) + r] = pq[q];
                    if (c != 4 && c != 9) {
                        const int rl = r - ((c >= 5) ? GG : 0);
                        box_l[I * (8 * GG) + rl] = lq[q];
                    }
                }
            }
        }
    }
    __syncthreads();

    // ---- per-cell box loss from LDS (lanes 0..48, both wave images) ----
    if (lane < GG) {
#pragma unroll
        for (int im = 0; im < IPW; ++im) {
            const int I = wimg + im;
            const float* bp = &box_p[I * (10 * GG)];
            const float* bl = &box_l[I * (8 * GG)];

            float pv[10];
#pragma unroll
            for (int c = 0; c < 10; ++c) pv[c] = bp[c * GG + lane];
            const float lv0 = bl[0 * GG + lane], lv1 = bl[1 * GG + lane];
            const float lv2 = bl[2 * GG + lane], lv3 = bl[3 * GG + lane];
            const float lv5 = bl[4 * GG + lane], lv6 = bl[5 * GG + lane];
            const float lv7 = bl[6 * GG + lane], lv8 = bl[7 * GG + lane];
            const float obj = obj_s[I * GG + lane];

            const int m = lane / G;
            const int n = lane - m * G;
            const float gx = (float)m, gy = (float)n;
            const float inv7 = 1.0f / 7.0f;

            const float cx1 = (pv[0] + gx) * inv7, cy1 = (pv[1] + gy) * inv7;
            const float hw1 = 0.5f * pv[2],        hh1 = 0.5f * pv[3];
            const float a1x1 = cx1 - hw1, a1y1 = cy1 - hh1, a1x2 = cx1 + hw1, a1y2 = cy1 + hh1;
            const float cx2 = (pv[5] + gx) * inv7, cy2 = (pv[6] + gy) * inv7;
            const float hw2 = 0.5f * pv[7],        hh2 = 0.5f * pv[8];
            const float a2x1 = cx2 - hw2, a2y1 = cy2 - hh2, a2x2 = cx2 + hw2, a2y2 = cy2 + hh2;
            const float cxg = (lv0 + gx) * inv7,   cyg = (lv1 + gy) * inv7;
            const float hwg = 0.5f * lv2,          hhg = 0.5f * lv3;
            const float bx1 = cxg - hwg, by1 = cyg - hhg, bx2 = cxg + hwg, by2 = cyg + hhg;

            const float area_g = (bx2 - bx1) * (by2 - by1);

            float ix1 = fmaxf(a1x1, bx1), iy1 = fmaxf(a1y1, by1);
            float ix2 = fminf(a1x2, bx2), iy2 = fminf(a1y2, by2);
            float inter1 = fmaxf(ix2 - ix1, 0.0f) * fmaxf(iy2 - iy1, 0.0f);
            float area1  = (a1x2 - a1x1) * (a1y2 - a1y1);
            float iou1 = (inter1 > 0.0f) ? inter1 / (area1 + area_g - inter1) : 0.0f;

            ix1 = fmaxf(a2x1, bx1); iy1 = fmaxf(a2y1, by1);
            ix2 = fminf(a2x2, bx2); iy2 = fminf(a2y2, by2);
            float inter2 = fmaxf(ix2 - ix1, 0.0f) * fmaxf(iy2 - iy1, 0.0f);
            float area2  = (a2x2 - a2x1) * (a2y2 - a2y1);
            float iou2 = (inter2 > 0.0f) ? inter2 / (area2 + area_g - inter2) : 0.0f;

            const bool resp1 = iou1 > iou2;

            const float coor1 = sq(pv[0] - lv0) + sq(pv[1] - lv1)
                              + sq(sqrtf(pv[2]) - sqrtf(lv2)) + sq(sqrtf(pv[3]) - sqrtf(lv3));
            const float coor2 = sq(pv[5] - lv5) + sq(pv[6] - lv6)
                              + sq(sqrtf(pv[7]) - sqrtf(lv7)) + sq(sqrtf(pv[8]) - sqrtf(lv8));
            const float coor = resp1 ? coor1 : coor2;

            const float e1 = sq(pv[4] - iou1);
            const float e2 = sq(pv[9] - iou2);
            const float obj_conf   = resp1 ? e1 : e2;
            const float noobj_resp = resp1 ? e2 : e1;

            acc += obj * (5.0f * coor + obj_conf + 0.5f * noobj_resp)
                 + (1.0f - obj) * 0.5f * (pv[4] * pv[4] + pv[9] * pv[9]);
        }
    }

    // ---- reduce: wave(64) shuffle -> LDS -> one partial per block ----
#pragma unroll
    for (int off = 32; off > 0; off >>= 1) acc += __shfl_down(acc, off, 64);

    if (lane == 0) wsum[wid] = acc;
    __syncthreads();
    if (t == 0) ws[blockIdx.x] = wsum[0] + wsum[1] + wsum[2] + wsum[3];
}

__global__ __launch_bounds__(TPB) void yolo_loss_final(
    const float* __restrict__ ws, float* __restrict__ out)
{
    const int t = threadIdx.x;
    const float4* w4 = (const float4*)ws;
    float4 a = make_float4(0.f, 0.f, 0.f, 0.f);
#pragma unroll
    for (int j = 0; j < NBLK / 4 / TPB; ++j) {   // 2048/4/256 = 2 exact
        float4 x = w4[t + j * TPB];
        a.x += x.x; a.y += x.y; a.z += x.z; a.w += x.w;
    }
    float v = (a.x + a.y) + (a.z + a.w);
#pragma unroll
    for (int off = 32; off > 0; off >>= 1) v += __shfl_down(v, off, 64);

    __shared__ float wsum[TPB / 64];
    const int lane = t & 63;
    const int wid  = t >> 6;
    if (lane == 0) wsum[wid] = v;
    __syncthreads();
    if (t == 0) {
        // faithful reference quirk: divide by (N-1) == 6, not batch size
        out[0] = (wsum[0] + wsum[1] + wsum[2] + wsum[3]) * (1.0f / 6.0f);
    }
}

extern "C" void kernel_launch(void* const* d_in, const int* in_sizes, int n_in,
                              void* d_out, int out_size, void* d_ws, size_t ws_size,
                              hipStream_t stream) {
    const float* pred = (const float*)d_in[0];
    const float* lab  = (const float*)d_in[1];
    float* ws  = (float*)d_ws;
    float* out = (float*)d_out;

    yolo_loss_partial<<<NBLK, TPB, 0, stream>>>(pred, lab, ws);
    yolo_loss_final<<<1, TPB, 0, stream>>>(ws, out);
}

// Round 6
// 202.536 us; speedup vs baseline: 1.0388x; 1.0388x over previous
//
#include <hip/hip_runtime.h>

// YOLOv1 loss, fused, async global->LDS (global_load_lds dwordx4) staging.
// pred, labels: [B=16384, C=30, G=7, G=7] fp32, contiguous. Output: scalar fp32.
// Block = 256 threads owns IPB=2 whole images (2*1470 floats per tensor,
// contiguous), DMA-staged to LDS; threads 0..97 each compute one cell.
//
// Session finding (R1-R5): six structurally distinct kernels all pin at
// 2.5-2.7 TB/s total read service rate, invariant to HBM-vs-L3 mix ->
// read-direction fabric ceiling ~3 TB/s. This structure is the measured
// optimum (71 us = 2.72 TB/s). Bytes are minimal; no lever remains.

constexpr int BATCH  = 16384;
constexpr int CH     = 30;
constexpr int G      = 7;
constexpr int GG     = G * G;            // 49
constexpr int TPB    = 256;
constexpr int IPB    = 2;                // images per block
constexpr int IMG_F  = CH * GG;          // 1470 floats per image per tensor
constexpr int BLK_F  = IPB * IMG_F;      // 2940 floats per tensor per block
constexpr int BLK_V4 = BLK_F / 4;        // 735 float4s per tensor
constexpr int NBLK   = BATCH / IPB;      // 8192 blocks (exact)
constexpr int FULL_IT = BLK_V4 / TPB;    // 2 full staging iterations
constexpr int TAIL    = BLK_V4 - FULL_IT * TPB;  // 223 tail elements

__device__ __forceinline__ float sq(float x) { return x * x; }

// Async 16B/lane global->LDS DMA. LDS dest = (wave-uniform base) + lane*16.
__device__ __forceinline__ void async_copy16(const float4* gsrc, float4* ldst) {
    __builtin_amdgcn_global_load_lds(
        (const __attribute__((address_space(1))) void*)gsrc,
        (__attribute__((address_space(3))) void*)ldst,
        16, 0, 0);
}

__global__ __launch_bounds__(TPB) void yolo_loss_partial(
    const float* __restrict__ pred,
    const float* __restrict__ lab,
    float* __restrict__ ws)
{
    __shared__ float4 sp4[BLK_V4];
    __shared__ float4 sl4[BLK_V4];
    __shared__ float wsum[TPB / 64];

    const int t = threadIdx.x;
    const int wbase = t & ~63;           // wave-uniform lane-0 element index
    const float4* gp = (const float4*)(pred + (size_t)blockIdx.x * BLK_F);
    const float4* gl = (const float4*)(lab  + (size_t)blockIdx.x * BLK_F);

    // ---- stage via async DMA: no VGPR round-trip, nothing to spill ----
#pragma unroll
    for (int it = 0; it < FULL_IT; ++it)
        async_copy16(gp + it * TPB + t, sp4 + it * TPB + wbase);
    if (t < TAIL)
        async_copy16(gp + FULL_IT * TPB + t, sp4 + FULL_IT * TPB + wbase);
#pragma unroll
    for (int it = 0; it < FULL_IT; ++it)
        async_copy16(gl + it * TPB + t, sl4 + it * TPB + wbase);
    if (t < TAIL)
        async_copy16(gl + FULL_IT * TPB + t, sl4 + FULL_IT * TPB + wbase);

    __syncthreads();   // compiler drains vmcnt before s_barrier (m97 pattern)

    const float* sp = (const float*)sp4;
    const float* sl = (const float*)sl4;

    // ---- compute: one cell per thread (threads 0..97) ----
    float cell_loss = 0.0f;
    if (t < IPB * GG) {
        const int img  = t / GG;
        const int cell = t - img * GG;
        const int m    = cell / G;        // grid index along dim -2
        const int n    = cell - m * G;    // grid index along dim -1

        const float* p = sp + img * IMG_F + cell;
        const float* l = sl + img * IMG_F + cell;

        float pv[10];
#pragma unroll
        for (int c = 0; c < 10; ++c) pv[c] = p[c * GG];
        float lv[9];
#pragma unroll
        for (int c = 0; c < 9; ++c) lv[c] = l[c * GG];

        float cls = 0.0f;
#pragma unroll
        for (int c = 10; c < 30; ++c) {
            float d = p[c * GG] - l[c * GG];
            cls += d * d;
        }

        const float gx = (float)m;
        const float gy = (float)n;
        const float inv7 = 1.0f / 7.0f;

        // box1 (pred ch 0..3)
        const float cx1 = (pv[0] + gx) * inv7, cy1 = (pv[1] + gy) * inv7;
        const float hw1 = 0.5f * pv[2],        hh1 = 0.5f * pv[3];
        const float a1x1 = cx1 - hw1, a1y1 = cy1 - hh1, a1x2 = cx1 + hw1, a1y2 = cy1 + hh1;
        // box2 (pred ch 5..8)
        const float cx2 = (pv[5] + gx) * inv7, cy2 = (pv[6] + gy) * inv7;
        const float hw2 = 0.5f * pv[7],        hh2 = 0.5f * pv[8];
        const float a2x1 = cx2 - hw2, a2y1 = cy2 - hh2, a2x2 = cx2 + hw2, a2y2 = cy2 + hh2;
        // gt box (labels ch 0..3)
        const float cxg = (lv[0] + gx) * inv7, cyg = (lv[1] + gy) * inv7;
        const float hwg = 0.5f * lv[2],        hhg = 0.5f * lv[3];
        const float bx1 = cxg - hwg, by1 = cyg - hhg, bx2 = cxg + hwg, by2 = cyg + hhg;

        const float area_g = (bx2 - bx1) * (by2 - by1);

        // IOU(box1, gt)
        float ix1 = fmaxf(a1x1, bx1), iy1 = fmaxf(a1y1, by1);
        float ix2 = fminf(a1x2, bx2), iy2 = fminf(a1y2, by2);
        float inter1 = fmaxf(ix2 - ix1, 0.0f) * fmaxf(iy2 - iy1, 0.0f);
        float area1  = (a1x2 - a1x1) * (a1y2 - a1y1);
        float iou1 = (inter1 > 0.0f) ? inter1 / (area1 + area_g - inter1) : 0.0f;

        // IOU(box2, gt)
        ix1 = fmaxf(a2x1, bx1); iy1 = fmaxf(a2y1, by1);
        ix2 = fminf(a2x2, bx2); iy2 = fminf(a2y2, by2);
        float inter2 = fmaxf(ix2 - ix1, 0.0f) * fmaxf(iy2 - iy1, 0.0f);
        float area2  = (a2x2 - a2x1) * (a2y2 - a2y1);
        float iou2 = (inter2 > 0.0f) ? inter2 / (area2 + area_g - inter2) : 0.0f;

        const bool resp1 = iou1 > iou2;
        const float obj = (lv[4] == 1.0f) ? 1.0f : 0.0f;

        const float coor1 = sq(pv[0] - lv[0]) + sq(pv[1] - lv[1])
                          + sq(sqrtf(pv[2]) - sqrtf(lv[2])) + sq(sqrtf(pv[3]) - sqrtf(lv[3]));
        const float coor2 = sq(pv[5] - lv[5]) + sq(pv[6] - lv[6])
                          + sq(sqrtf(pv[7]) - sqrtf(lv[7])) + sq(sqrtf(pv[8]) - sqrtf(lv[8]));
        const float coor = resp1 ? coor1 : coor2;

        const float e1 = sq(pv[4] - iou1);
        const float e2 = sq(pv[9] - iou2);
        const float obj_conf   = resp1 ? e1 : e2;
        const float noobj_resp = resp1 ? e2 : e1;

        cell_loss = obj * (5.0f * coor + obj_conf + 0.5f * noobj_resp + cls)
                  + (1.0f - obj) * 0.5f * (pv[4] * pv[4] + pv[9] * pv[9]);
    }

    // ---- reduce: wave(64) shuffle -> LDS -> one partial per block ----
    float v = cell_loss;
#pragma unroll
    for (int off = 32; off > 0; off >>= 1) v += __shfl_down(v, off, 64);

    const int lane = t & 63;
    const int wid  = t >> 6;
    if (lane == 0) wsum[wid] = v;
    __syncthreads();
    if (t == 0) ws[blockIdx.x] = wsum[0] + wsum[1] + wsum[2] + wsum[3];
}

__global__ __launch_bounds__(TPB) void yolo_loss_final(
    const float* __restrict__ ws, float* __restrict__ out)
{
    const int t = threadIdx.x;
    const float4* w4 = (const float4*)ws;
    float4 a = make_float4(0.f, 0.f, 0.f, 0.f);
#pragma unroll
    for (int j = 0; j < NBLK / 4 / TPB; ++j) {   // 8192/4/256 = 8 exact
        float4 x = w4[t + j * TPB];
        a.x += x.x; a.y += x.y; a.z += x.z; a.w += x.w;
    }
    float v = (a.x + a.y) + (a.z + a.w);
#pragma unroll
    for (int off = 32; off > 0; off >>= 1) v += __shfl_down(v, off, 64);

    __shared__ float wsum[TPB / 64];
    const int lane = t & 63;
    const int wid  = t >> 6;
    if (lane == 0) wsum[wid] = v;
    __syncthreads();
    if (t == 0) {
        // faithful reference quirk: divide by (N-1) == 6, not batch size
        out[0] = (wsum[0] + wsum[1] + wsum[2] + wsum[3]) * (1.0f / 6.0f);
    }
}

extern "C" void kernel_launch(void* const* d_in, const int* in_sizes, int n_in,
                              void* d_out, int out_size, void* d_ws, size_t ws_size,
                              hipStream_t stream) {
    const float* pred = (const float*)d_in[0];
    const float* lab  = (const float*)d_in[1];
    float* ws  = (float*)d_ws;
    float* out = (float*)d_out;

    yolo_loss_partial<<<NBLK, TPB, 0, stream>>>(pred, lab, ws);
    yolo_loss_final<<<1, TPB, 0, stream>>>(ws, out);
}